// Round 10
// baseline (397.840 us; speedup 1.0000x reference)
//
#include <hip/hip_runtime.h>

#define EMB 256
typedef unsigned short u16;
typedef __attribute__((ext_vector_type(8))) short short8v;
typedef __attribute__((ext_vector_type(4))) short short4v;
typedef __attribute__((ext_vector_type(4))) float f32x4;

__device__ inline u16 f2bf(float x){
  union{float f; unsigned u;} c; c.f = x;
  unsigned r = c.u + 0x7FFFu + ((c.u>>16)&1u);
  return (u16)(r>>16);
}
__device__ inline float bf2f(u16 h){
  union{unsigned u; float f;} c; c.u = ((unsigned)h) << 16; return c.f;
}

// ---------------- DDE: counts + round-1 scatter fused ----------------
__global__ void k_scatter1(const int* __restrict__ h_id, const int* __restrict__ t_id,
                           const float* __restrict__ topic,
                           float* __restrict__ cnt_f, float* __restrict__ cnt_r,
                           float* __restrict__ accf, float* __restrict__ accr, int E) {
  int e = blockIdx.x * 256 + threadIdx.x;
  if (e >= E) return;
  int h = h_id[e], t = t_id[e];
  atomicAdd(&cnt_f[t], 1.0f);
  atomicAdd(&cnt_r[h], 1.0f);
  float a0 = topic[2*h+0], a1 = topic[2*h+1];
  if (a0 != 0.f) atomicAdd(&accf[2*t+0], a0);
  if (a1 != 0.f) atomicAdd(&accf[2*t+1], a1);
  float c0 = topic[2*t+0], c1 = topic[2*t+1];
  if (c0 != 0.f) atomicAdd(&accr[2*h+0], c0);
  if (c1 != 0.f) atomicAdd(&accr[2*h+1], c1);
}

// block 0: gate softmax + qpart; blocks 1..gN: div1
__global__ void k_div1_gate(const float* __restrict__ topic,
                            const float* __restrict__ cnt_f, const float* __restrict__ cnt_r,
                            const float* __restrict__ accf, const float* __restrict__ accr,
                            float* __restrict__ pos, int N,
                            const float* __restrict__ q, const float* __restrict__ Wg,
                            const float* __restrict__ bg, const float* __restrict__ W1,
                            const float* __restrict__ b1, float* __restrict__ gateq) {
  int t = threadIdx.x;
  if (blockIdx.x == 0) {
    __shared__ float qs[256];
    __shared__ float z[3];
    qs[t] = q[t];
    __syncthreads();
    if (t < 3) {
      float s = bg[t];
      for (int k = 0; k < 256; ++k) s += qs[k] * Wg[k*3 + t];
      z[t] = s;
    }
    __syncthreads();
    if (t == 0) {
      float m = fmaxf(z[0], fmaxf(z[1], z[2]));
      float e0 = expf(z[0]-m), e1 = expf(z[1]-m), e2 = expf(z[2]-m);
      float s = e0 + e1 + e2;
      gateq[0] = e0/s; gateq[1] = e1/s; gateq[2] = e2/s; gateq[3] = 0.f;
    }
    float a = b1[t];
    for (int k = 0; k < 256; ++k) a += qs[k] * W1[k*256 + t];
    gateq[4 + t] = a;
    return;
  }
  int n = (blockIdx.x - 1) * 256 + t;
  if (n >= N) return;
  float cf = fmaxf(cnt_f[n], 1.0f), cr = fmaxf(cnt_r[n], 1.0f);
  pos[10*n+0] = topic[2*n+0];
  pos[10*n+1] = topic[2*n+1];
  pos[10*n+2] = accf[2*n+0] / cf;
  pos[10*n+3] = accf[2*n+1] / cf;
  pos[10*n+6] = accr[2*n+0] / cr;
  pos[10*n+7] = accr[2*n+1] / cr;
}

__global__ void k_scatter2(const int* __restrict__ h_id, const int* __restrict__ t_id,
                           const float* __restrict__ pos,
                           float* __restrict__ accf, float* __restrict__ accr, int E) {
  int e = blockIdx.x * 256 + threadIdx.x;
  if (e >= E) return;
  int h = h_id[e], t = t_id[e];
  float a0 = pos[10*h+2], a1 = pos[10*h+3];
  if (a0 != 0.f) atomicAdd(&accf[2*t+0], a0);
  if (a1 != 0.f) atomicAdd(&accf[2*t+1], a1);
  float c0 = pos[10*t+6], c1 = pos[10*t+7];
  if (c0 != 0.f) atomicAdd(&accr[2*h+0], c0);
  if (c1 != 0.f) atomicAdd(&accr[2*h+1], c1);
}

__global__ void k_div2(const float* __restrict__ cnt_f, const float* __restrict__ cnt_r,
                       const float* __restrict__ accf, const float* __restrict__ accr,
                       float* __restrict__ pos, int N) {
  int n = blockIdx.x * 256 + threadIdx.x;
  if (n >= N) return;
  float cf = fmaxf(cnt_f[n], 1.0f), cr = fmaxf(cnt_r[n], 1.0f);
  pos[10*n+4] = accf[2*n+0] / cf;
  pos[10*n+5] = accf[2*n+1] / cf;
  pos[10*n+8] = accr[2*n+0] / cr;
  pos[10*n+9] = accr[2*n+1] / cr;
}

// ---------------- weight transforms (gate-folded) ----------------
__global__ void k_wtrans(const float* __restrict__ Wpos, const float* __restrict__ Wstr,
                         const float* __restrict__ W1, const float* __restrict__ Wnb,
                         const float* __restrict__ bpos, const float* __restrict__ gateq,
                         u16* __restrict__ WB, u16* __restrict__ WN) {
  int gid = blockIdx.x * 256 + threadIdx.x;
  if (gid < 11*1024) {
    int lane = gid & 63, ft = (gid >> 6) & 15, kt = gid >> 10;
    int n  = ft*16 + (lane & 15);
    int k0 = (lane >> 4) * 8;
    short8v v;
    if (kt == 0) {
      float g1 = gateq[1];
      #pragma unroll
      for (int j = 0; j < 8; ++j) {
        int k = k0 + j;
        float x = (k < 20) ? g1 * Wpos[(size_t)k*256 + n]
                : (k == 20) ? g1 * bpos[n] : 0.f;
        v[j] = (short)f2bf(x);
      }
    } else if (kt < 3) {
      float g2 = gateq[2];
      int kbase = (kt-1)*32;
      #pragma unroll
      for (int j = 0; j < 8; ++j)
        v[j] = (short)f2bf(g2 * Wstr[(size_t)(256 + kbase + k0 + j)*256 + n]);
    } else {
      int kbase = (kt-3)*32;
      #pragma unroll
      for (int j = 0; j < 8; ++j)
        v[j] = (short)f2bf(W1[(size_t)(256 + kbase + k0 + j)*256 + n]);
    }
    *(short8v*)(WB + (size_t)gid * 8) = v;
  } else {
    int g2i = gid - 11*1024;
    if (g2i >= 8*32*64) return;
    int lane = g2i & 63, nt = (g2i >> 6) & 31, kc = g2i >> 11;
    int col = nt*16 + (lane & 15);
    int k0  = kc*32 + (lane >> 4) * 8;
    short8v v;
    #pragma unroll
    for (int j = 0; j < 8; ++j) {
      int k = k0 + j;
      float x = (col < 256) ? Wnb[(size_t)k*256 + col] : Wnb[(size_t)(256+k)*256 + (col-256)];
      v[j] = (short)f2bf(x);
    }
    *(short8v*)(WN + (size_t)g2i * 8) = v;
  }
}

// ---------------- node tables + S, fused (gate/bias-folded) ----------------
__global__ __launch_bounds__(512) void k_node_S(const float* __restrict__ ent,
                                                const float* __restrict__ ntx,
                                                const u16* __restrict__ WN,
                                                u16* __restrict__ TA, u16* __restrict__ TB,
                                                int NT, int nNodeBlk,
                                                const float* __restrict__ rel,
                                                const float* __restrict__ Wstr,
                                                const float* __restrict__ b_nb,
                                                const float* __restrict__ b_str,
                                                const float* __restrict__ gateq,
                                                float* __restrict__ S) {
  const int t = threadIdx.x;
  if ((int)blockIdx.x >= nNodeBlk) {
    __shared__ float rs[2][256];
    int half = t >> 8, tc = t & 255;
    int r = (blockIdx.x - nNodeBlk) * 2 + half;
    rs[half][tc] = rel[(size_t)r*256 + tc];
    __syncthreads();
    float a = 0.f;
    for (int k = 0; k < 256; ++k) a = fmaf(rs[half][k], Wstr[(size_t)k*256 + tc], a);
    S[(size_t)r*256 + tc] = gateq[2] * (a + b_str[tc]);
    return;
  }
  __shared__ __align__(16) u16 AF[4*64*8];
  __shared__ __align__(16) u16 TT[64*512];
  const int wv = t >> 6, l = t & 63;
  const int lr = l & 15, lg = l >> 4;
  const int nb0 = blockIdx.x * 64;
  const float g0 = gateq[0];

  const int mt = t >> 7, half = (t >> 6) & 1, l2 = t & 63;
  int snode = nb0 + mt*16 + (l2 & 15);
  const float* srow = (snode < NT) ? (ent + (size_t)snode * EMB) : ntx;

  f32x4 acc[4][4];
  #pragma unroll
  for (int m = 0; m < 4; ++m)
    #pragma unroll
    for (int n = 0; n < 4; ++n) acc[m][n] = (f32x4){0.f,0.f,0.f,0.f};

  for (int kc = 0; kc < 8; ++kc) {
    {
      int k = kc*32 + (l2 >> 4)*8 + half*4;
      float4 a4 = *(const float4*)(srow + k);
      short4v v;
      v[0]=(short)f2bf(a4.x); v[1]=(short)f2bf(a4.y);
      v[2]=(short)f2bf(a4.z); v[3]=(short)f2bf(a4.w);
      *(short4v*)&AF[((mt*64 + l2)*8 + half*4)] = v;
    }
    __syncthreads();
    short8v bn[4], af[4];
    #pragma unroll
    for (int n = 0; n < 4; ++n)
      bn[n] = *(const short8v*)&WN[((size_t)(kc*32 + wv*4 + n)*64 + l)*8];
    #pragma unroll
    for (int m = 0; m < 4; ++m)
      af[m] = *(const short8v*)&AF[(m*64 + l)*8];
    #pragma unroll
    for (int m = 0; m < 4; ++m)
      #pragma unroll
      for (int n = 0; n < 4; ++n)
        acc[m][n] = __builtin_amdgcn_mfma_f32_16x16x32_bf16(af[m], bn[n], acc[m][n], 0, 0, 0);
    __syncthreads();
  }
  #pragma unroll
  for (int m = 0; m < 4; ++m)
    #pragma unroll
    for (int n = 0; n < 4; ++n) {
      int col = wv*64 + n*16 + lr;
      float bias = (col < 256) ? b_nb[col] : 0.f;
      #pragma unroll
      for (int r2 = 0; r2 < 4; ++r2)
        TT[(m*16 + lg*4 + r2)*512 + col] = f2bf(g0 * (acc[m][n][r2] + bias));
    }
  __syncthreads();
  #pragma unroll
  for (int p = 0; p < 8; ++p) {
    int idx = p*512 + t;
    int nrow = idx >> 6, grp = idx & 63, col = grp*8;
    int node = nb0 + nrow;
    if (node <= NT) {
      uint4 v = *(const uint4*)&TT[nrow*512 + col];
      u16* dst = (col < 256) ? (TA + (size_t)node*256 + col)
                             : (TB + (size_t)node*256 + (col-256));
      *(uint4*)dst = v;
    }
  }
}

// ---------------- main kernel: 64 edges/block, 4 waves (2Mw x 2Nw) ----------------
// Quarter-size blocks -> 4 independent blocks/CU to overlap serial phases.
__global__ __launch_bounds__(256, 4)
void k_main(
    const int* __restrict__ h_id, const int* __restrict__ r_id, const int* __restrict__ t_id,
    const int* __restrict__ mids, const float* __restrict__ mwts,
    const float* __restrict__ motif,
    const float* __restrict__ W2, const float* __restrict__ b2,
    const float* __restrict__ pos, const float* __restrict__ gateq,
    const u16* __restrict__ WB, const float* __restrict__ S,
    const u16* __restrict__ TA, const u16* __restrict__ TB,
    float* __restrict__ out, int E, int NT)
{
  __shared__ __align__(16) u16 FT2[8*4*64*8];   // fused [k=256][edge=64] frag order (32 KB)
  __shared__ __align__(16) u16 XB[4*64*8];      // one staged B chunk (4 KB)
  __shared__ int ridsh[64];
  __shared__ float woacc[2][64];

  const int t  = threadIdx.x;
  const int wv = t >> 6, l = t & 63;
  const int Mw = wv >> 1, Nw = wv & 1;          // 2 x 2 wave grid
  const int lr = l & 15, lg = l >> 4;
  const int be = blockIdx.x * 64;

  int eo = be + wv*16 + lr; if (eo >= E) eo = E - 1;
  const int hid = h_id[eo], tid = t_id[eo];
  if (t < 64) {
    int e = be + t; if (e >= E) e = E - 1;
    ridsh[t] = r_id[e];
  }

  // motif ids/weights (vectorized)
  int4   mi0 = *(const int4*)  (mids + (size_t)eo*8);
  int4   mi1 = *(const int4*)  (mids + (size_t)eo*8 + 4);
  float4 mw0 = *(const float4*)(mwts + (size_t)eo*8);
  float4 mw1 = *(const float4*)(mwts + (size_t)eo*8 + 4);

  // ===== issue TA gathers async -> FT2 (dst = kc*4096 + wv*1024 bytes, wave-uniform) =====
  {
    const int hc = (hid < NT) ? hid : NT;
    const u16* paw = TA + (size_t)hc*256 + lg*8;
    #pragma unroll
    for (int kc = 0; kc < 8; ++kc)
      __builtin_amdgcn_global_load_lds(
        (const __attribute__((address_space(1))) unsigned int*)(paw + kc*32),
        (__attribute__((address_space(3))) unsigned int*)&FT2[(size_t)kc*2048 + wv*512],
        16, 0, 0);
  }

  // ===== stage pos chunk -> XB (k==20 -> 1.0 bias row) =====
  {
    float vals[8];
    #pragma unroll
    for (int jp = 0; jp < 4; ++jp) {
      int k2 = lg*8 + jp*2;
      float2 f2;
      if (k2 < 10)       f2 = *(const float2*)&pos[(size_t)hid*10 + k2];
      else if (k2 < 20)  f2 = *(const float2*)&pos[(size_t)tid*10 + (k2 - 10)];
      else if (k2 == 20) f2 = make_float2(1.f, 0.f);
      else               f2 = make_float2(0.f, 0.f);
      vals[jp*2] = f2.x; vals[jp*2+1] = f2.y;
    }
    short8v v;
    #pragma unroll
    for (int j = 0; j < 8; ++j) v[j] = (short)f2bf(vals[j]);
    *(short8v*)&XB[(wv*64 + l)*8] = v;
  }

  // ===== nb channel: TB via regs (2-ahead), TA from LDS; FT2 = relu(ta+tb) =====
  {
    const int tc2 = (tid < NT) ? tid : NT;
    const u16* pbw = TB + (size_t)tc2*256 + lg*8;
    short8v tb0 = *(const short8v*)(pbw);
    short8v tb1 = *(const short8v*)(pbw + 32);
    asm volatile("s_waitcnt vmcnt(0)" ::: "memory");
    __builtin_amdgcn_sched_barrier(0);
    #pragma unroll
    for (int kk = 0; kk < 8; kk += 2) {
      short8v nba = tb0, nbb = tb1;
      if (kk < 6) {
        tb0 = *(const short8v*)(pbw + (kk+2)*32);
        tb1 = *(const short8v*)(pbw + (kk+3)*32);
      }
      #pragma unroll
      for (int c2 = 0; c2 < 2; ++c2) {
        short8v nb = c2 ? nbb : nba;
        u16* slot = &FT2[(size_t)((kk+c2)*4 + wv)*512 + l*8];
        short8v o = *(const short8v*)slot;
        short8v w;
        #pragma unroll
        for (int j = 0; j < 8; ++j)
          w[j] = (short)f2bf(fmaxf(bf2f((u16)o[j]) + bf2f((u16)nb[j]), 0.f));
        *(short8v*)slot = w;
      }
    }
  }

  f32x4 acc[8][2];
  auto zacc = [&]() {
    #pragma unroll
    for (int m = 0; m < 8; ++m)
      #pragma unroll
      for (int n = 0; n < 2; ++n) acc[m][n] = (f32x4){0.f,0.f,0.f,0.f};
  };
  auto mfma_chunk = [&](const u16* wc) {
    short8v bfr[2];
    #pragma unroll
    for (int n = 0; n < 2; ++n)
      bfr[n] = *(const short8v*)&XB[((Nw*2 + n)*64 + l)*8];
    #pragma unroll
    for (int mh = 0; mh < 8; mh += 4) {
      short8v af[4];
      #pragma unroll
      for (int mm = 0; mm < 4; ++mm)
        af[mm] = *(const short8v*)&wc[((Mw*8 + mh + mm)*64 + l)*8];
      #pragma unroll
      for (int mm = 0; mm < 4; ++mm)
        #pragma unroll
        for (int n = 0; n < 2; ++n)
          acc[mh+mm][n] = __builtin_amdgcn_mfma_f32_16x16x32_bf16(af[mm], bfr[n], acc[mh+mm][n], 0, 0, 0);
    }
  };

  zacc();
  __syncthreads();                 // FT2 nb writes + XB pos stage visible

  // ===== pos: MFMA + RMW combine =====
  mfma_chunk(WB);
  {
    #pragma unroll
    for (int m = 0; m < 8; ++m) {
      int kc  = Mw*4 + ((m*4 + lg) >> 3);
      int lg2 = (m*2 + (lg >> 1)) & 3;
      #pragma unroll
      for (int n = 0; n < 2; ++n) {
        int nt = Nw*2 + n;
        int idx = ((kc*4 + nt)*64 + lg2*16 + lr)*8 + (lg & 1)*4;
        short4v o = *(const short4v*)&FT2[idx];
        short4v w;
        w[0] = (short)f2bf(bf2f((u16)o[0]) + fmaxf(acc[m][n][0], 0.f));
        w[1] = (short)f2bf(bf2f((u16)o[1]) + fmaxf(acc[m][n][1], 0.f));
        w[2] = (short)f2bf(bf2f((u16)o[2]) + fmaxf(acc[m][n][2], 0.f));
        w[3] = (short)f2bf(bf2f((u16)o[3]) + fmaxf(acc[m][n][3], 0.f));
        *(short4v*)&FT2[idx] = w;
      }
    }
  }
  zacc();
  __syncthreads();                 // XB free for motif

  // ===== motif: 2 chunks (K=64) =====
  auto stage_motif = [&](int cc) {
    int d0 = cc*32 + lg*8;
    int   idv[8] = {mi0.x,mi0.y,mi0.z,mi0.w,mi1.x,mi1.y,mi1.z,mi1.w};
    float wtv[8] = {mw0.x,mw0.y,mw0.z,mw0.w,mw1.x,mw1.y,mw1.z,mw1.w};
    float s[8] = {0,0,0,0,0,0,0,0};
    #pragma unroll
    for (int jt = 0; jt < 8; ++jt) {
      if (idv[jt] != 0) {
        const float4* mp = (const float4*)(motif + (size_t)idv[jt]*64 + d0);
        float4 a = mp[0], b = mp[1];
        float wt = wtv[jt];
        s[0] = fmaf(a.x, wt, s[0]); s[1] = fmaf(a.y, wt, s[1]);
        s[2] = fmaf(a.z, wt, s[2]); s[3] = fmaf(a.w, wt, s[3]);
        s[4] = fmaf(b.x, wt, s[4]); s[5] = fmaf(b.y, wt, s[5]);
        s[6] = fmaf(b.z, wt, s[6]); s[7] = fmaf(b.w, wt, s[7]);
      }
    }
    short8v v;
    #pragma unroll
    for (int i = 0; i < 8; ++i) v[i] = (short)f2bf(s[i]);
    *(short8v*)&XB[(wv*64 + l)*8] = v;
  };
  stage_motif(0);
  __syncthreads();
  mfma_chunk(WB + 1*8192);
  __syncthreads();
  stage_motif(1);
  __syncthreads();
  mfma_chunk(WB + 2*8192);
  // combine struct: S (pre-scaled g2, bias folded) + motif acc
  {
    #pragma unroll
    for (int m = 0; m < 8; ++m) {
      int f0 = Mw*128 + m*16 + lg*4;
      int kc  = Mw*4 + ((m*4 + lg) >> 3);
      int lg2 = (m*2 + (lg >> 1)) & 3;
      #pragma unroll
      for (int n = 0; n < 2; ++n) {
        int nt = Nw*2 + n;
        int r = ridsh[nt*16 + lr];
        float4 sv = *(const float4*)&S[(size_t)r*256 + f0];
        int idx = ((kc*4 + nt)*64 + lg2*16 + lr)*8 + (lg & 1)*4;
        short4v o = *(const short4v*)&FT2[idx];
        short4v w;
        w[0] = (short)f2bf(bf2f((u16)o[0]) + fmaxf(acc[m][n][0] + sv.x, 0.f));
        w[1] = (short)f2bf(bf2f((u16)o[1]) + fmaxf(acc[m][n][1] + sv.y, 0.f));
        w[2] = (short)f2bf(bf2f((u16)o[2]) + fmaxf(acc[m][n][2] + sv.z, 0.f));
        w[3] = (short)f2bf(bf2f((u16)o[3]) + fmaxf(acc[m][n][3] + sv.w, 0.f));
        *(short4v*)&FT2[idx] = w;
      }
    }
  }

  // ===== layer 1: acc init = qpart, B = FT2, A = W1 chunks 3..10 =====
  #pragma unroll
  for (int m = 0; m < 8; ++m) {
    int f0 = Mw*128 + m*16 + lg*4;
    f32x4 qv = { gateq[4+f0], gateq[5+f0], gateq[6+f0], gateq[7+f0] };
    #pragma unroll
    for (int n = 0; n < 2; ++n) acc[m][n] = qv;
  }
  __syncthreads();                 // FT2 final for cross-wave L1 reads
  for (int c2 = 0; c2 < 8; ++c2) {
    const u16* wc = WB + (size_t)(3 + c2) * 8192;
    short8v bfr[2];
    #pragma unroll
    for (int n = 0; n < 2; ++n)
      bfr[n] = *(const short8v*)&FT2[((c2*4 + Nw*2 + n)*64 + l)*8];
    #pragma unroll
    for (int mh = 0; mh < 8; mh += 4) {
      short8v af[4];
      #pragma unroll
      for (int mm = 0; mm < 4; ++mm)
        af[mm] = *(const short8v*)&wc[((Mw*8 + mh + mm)*64 + l)*8];
      #pragma unroll
      for (int mm = 0; mm < 4; ++mm)
        #pragma unroll
        for (int n = 0; n < 2; ++n)
          acc[mh+mm][n] = __builtin_amdgcn_mfma_f32_16x16x32_bf16(af[mm], bfr[n], acc[mh+mm][n], 0, 0, 0);
    }
  }

  // ===== layer 2 =====
  {
    #pragma unroll
    for (int n = 0; n < 2; ++n) {
      float p = 0.f;
      #pragma unroll
      for (int m = 0; m < 8; ++m) {
        int f0 = Mw*128 + m*16 + lg*4;
        float4 w4 = *(const float4*)&W2[f0];
        p = fmaf(fmaxf(acc[m][n][0], 0.f), w4.x, p);
        p = fmaf(fmaxf(acc[m][n][1], 0.f), w4.y, p);
        p = fmaf(fmaxf(acc[m][n][2], 0.f), w4.z, p);
        p = fmaf(fmaxf(acc[m][n][3], 0.f), w4.w, p);
      }
      p += __shfl_xor(p, 16);
      p += __shfl_xor(p, 32);
      if (lg == 0) woacc[Mw][Nw*32 + n*16 + lr] = p;
    }
  }
  __syncthreads();
  if (t < 64) {
    int e = be + t;
    if (e < E)
      out[e] = woacc[0][t] + woacc[1][t] + b2[0];
  }
}

extern "C" void kernel_launch(void* const* d_in, const int* in_sizes, int n_in,
                              void* d_out, int out_size, void* d_ws, size_t ws_size,
                              hipStream_t stream) {
  const int*   h_id  = (const int*)  d_in[0];
  const int*   r_id  = (const int*)  d_in[1];
  const int*   t_id  = (const int*)  d_in[2];
  const float* q     = (const float*)d_in[3];
  const float* ent   = (const float*)d_in[4];
  const float* rel   = (const float*)d_in[6];
  const float* topic = (const float*)d_in[7];
  const int*   mids  = (const int*)  d_in[8];
  const float* mwts  = (const float*)d_in[9];
  const float* ntx   = (const float*)d_in[10];
  const float* motif = (const float*)d_in[11];
  const float* W_nb  = (const float*)d_in[12];
  const float* b_nb  = (const float*)d_in[13];
  const float* W_pos = (const float*)d_in[14];
  const float* b_pos = (const float*)d_in[15];
  const float* W_str = (const float*)d_in[16];
  const float* b_str = (const float*)d_in[17];
  const float* W_g   = (const float*)d_in[18];
  const float* b_g   = (const float*)d_in[19];
  const float* W1    = (const float*)d_in[20];
  const float* b1    = (const float*)d_in[21];
  const float* W2    = (const float*)d_in[22];
  const float* b2    = (const float*)d_in[23];
  float* out = (float*)d_out;

  const int E  = in_sizes[0];
  const int NT = in_sizes[4] / EMB;   // 80000 text entities
  const int N  = in_sizes[7] / 2;     // 100000 total nodes

  float* ws    = (float*)d_ws;
  float* cnt_f = ws;
  float* cnt_r = ws + (size_t)N;
  float* a1f   = ws + (size_t)2*N;
  float* a1r   = ws + (size_t)4*N;
  float* a2f   = ws + (size_t)6*N;
  float* a2r   = ws + (size_t)8*N;
  float* pos   = ws + (size_t)10*N;             // N x 10
  float* gateq = ws + (size_t)20*N;             // [g0,g1,g2,pad, qpart(256)]
  u16*   WB    = (u16*)(ws + (size_t)20*N + 512);   // 11 chunks x 8192 u16
  u16*   WN    = WB + (size_t)11*8192;              // 8*32*64*8 = 131072 u16
  float* S     = (float*)(WN + 131072);             // 2000*256 f32
  u16*   TA    = (u16*)(S + (size_t)2000*256);      // (NT+1) x 256 bf16
  u16*   TB    = TA + (size_t)(NT+1)*256;

  hipMemsetAsync(d_ws, 0, (size_t)10 * N * sizeof(float), stream);

  int gE = (E + 255) / 256, gN = (N + 255) / 256;
  int nNodeBlk = (NT + 64) / 64;
  k_scatter1 <<<gE, 256, 0, stream>>>(h_id, t_id, topic, cnt_f, cnt_r, a1f, a1r, E);
  k_div1_gate<<<gN + 1, 256, 0, stream>>>(topic, cnt_f, cnt_r, a1f, a1r, pos, N,
                                          q, W_g, b_g, W1, b1, gateq);
  k_scatter2 <<<gE, 256, 0, stream>>>(h_id, t_id, pos, a2f, a2r, E);
  k_div2     <<<gN, 256, 0, stream>>>(cnt_f, cnt_r, a2f, a2r, pos, N);
  k_wtrans   <<<108, 256, 0, stream>>>(W_pos, W_str, W1, W_nb, b_pos, gateq, WB, WN);
  k_node_S   <<<nNodeBlk + 1000, 512, 0, stream>>>(ent, ntx, WN, TA, TB, NT, nNodeBlk,
                                                   rel, W_str, b_nb, b_str, gateq, S);

  int gM = (E + 63) / 64;
  k_main<<<gM, 256, 0, stream>>>(h_id, r_id, t_id, mids, mwts, motif,
                                 W2, b2, pos, gateq, WB, S, TA, TB, out, E, NT);
}